// Round 8
// baseline (1048.239 us; speedup 1.0000x reference)
//
#include <hip/hip_runtime.h>

// ---------------------------------------------------------------------------
// Grid attention v9, bf16 MFMA (gfx950). 4096 windows; n=49; D=512; 16h x 32.
// 512 threads = 8 waves; wave w owns heads {2w,2w+1} END-TO-END, wave-private.
// ONE __syncthreads (after x,y staging). Layout algebra:
//   Q^T = MFMA(A=Wq-frag, B=x-frag)  -> q transposed for free, never in LDS
//   K,V = MFMA(A=y-frag, B=W-frag)   -> k via small LDS transpose (3136B/wave)
//   sim^T = MFMA(A=k-frag, B=q^T-frag built by 8-shfl from Q^T C-frags)
//   softmax in-lane (i=lane) + shfl_xor(16,32); P normalized, packed in regs
//   PV: out^T = MFMA(A=V^T-frag, B=P^T-frag), both built by 8-shfl from regs
// LDS = 100352 staging + 8*3136 k-scratch = 125440 B.
// ws (2.5MB): Wq/Wk/Wv pre-swizzled B-frags + biasT (sim^T layout) -- as v8.
// ---------------------------------------------------------------------------

typedef __bf16 bf16x8 __attribute__((ext_vector_type(8)));
typedef __attribute__((ext_vector_type(4))) float f32x4;

#define DEVI __device__ __forceinline__

DEVI unsigned short f2bf(float f) {  // round-to-nearest-even
  union { float f; unsigned u; } v; v.f = f;
  unsigned r = v.u + 0x7FFFu + ((v.u >> 16) & 1u);
  return (unsigned short)(r >> 16);
}
DEVI unsigned pkbf(float a, float b) {
  return (unsigned)f2bf(a) | ((unsigned)f2bf(b) << 16);
}

#define MFMA16(a, b, c) __builtin_amdgcn_mfma_f32_16x16x32_bf16((a), (b), (c), 0, 0, 0)
#define WAVE_DS_FENCE() do { asm volatile("s_waitcnt lgkmcnt(0)" ::: "memory"); \
                             __builtin_amdgcn_sched_barrier(0); } while (0)

#define SWZ_Y(r)  ((((unsigned)(r)) & 7u) << 4)
#define SWZ_A(r)  (((((unsigned)(r)) >> 2) & 3u) << 5)

// ---------------- prep: weights -> swizzled bf16 frags, bias -> sim^T layout
__global__ void prep_kernel(const float* __restrict__ Wq, const float* __restrict__ Wkv,
                            const float* __restrict__ bt, char* __restrict__ ws) {
  int t = blockIdx.x * 256 + threadIdx.x;
  if (t < 786432) {  // 3 * 16 * 2 * 16 * 64 * 8 bf16 elements
    int e = t & 7, lane = (t >> 3) & 63, ks = (t >> 9) & 15, nt = (t >> 13) & 1,
        h = (t >> 14) & 15, T = t >> 18;
    int row = ks * 32 + (lane >> 4) * 8 + e;     // K index in [0,512)
    int col = h * 32 + nt * 16 + (lane & 15);    // N index (dh)
    float v;
    if (T == 0)      v = Wq[row * 512 + col] * 0.17677669529663687f;  // fold 1/sqrt(32)
    else if (T == 1) v = Wkv[row * 1024 + col];
    else             v = Wkv[row * 1024 + 512 + col];
    ((unsigned short*)ws)[t] = f2bf(v);
  }
  if (t < 262144) {  // 16 * 4(i-tile) * 4(j-tile) * 64 * 4 f32, sim^T layout
    int r = t & 3, lane = (t >> 2) & 63, nt = (t >> 8) & 3, mt = (t >> 10) & 3,
        h = (t >> 12) & 15;
    int i = mt * 16 + (lane & 15);               // query: lane&15
    int j = nt * 16 + ((lane >> 4) & 3) * 4 + r; // key: regs
    float v;
    if (j >= 49)      v = -1e30f;   // mask padded key slots
    else if (i >= 49) v = 0.0f;     // padded query cols: keep finite
    else {
      int hi = i / 7, wi = i % 7, hj = j / 7, wj = j % 7;
      v = bt[((hi - hj + 6) * 13 + (wi - wj + 6)) * 16 + h];
    }
    ((float*)(ws + 1572864))[t] = v;
  }
}

// ---------------- LDS loaders ------------------------------------------------
DEVI bf16x8 ldXY(const char* base, int row, int kc) {
  unsigned a = ((unsigned)(row * 1024 + kc * 2)) ^ SWZ_Y(row);
  return *(const bf16x8*)(base + a);
}
DEVI bf16x8 ldXYc(const char* base, int row, int kc) {  // clamp (dup row 48)
  int rc = row < 48 ? row : 48;
  return ldXY(base, rc, kc);
}
// k scratch: [49][32] bf16, row stride 64B, swz SWZ_A
DEVI bf16x8 ldA(const char* base, int row, int kc) {
  int rc = row < 48 ? row : 48;
  unsigned a = ((unsigned)(rc * 64 + kc * 2)) ^ SWZ_A(rc);
  return *(const bf16x8*)(base + a);
}

// ---------------- register-shuffle fragment builder -------------------------
DEVI uint2 shfl_u2(uint2 v, int src) {
  uint2 r;
  r.x = (unsigned)__shfl((int)v.x, src);
  r.y = (unsigned)__shfl((int)v.y, src);
  return r;
}
// Build a bf16x8 MFMA operand (k = g*8+e) from two packed C-layout reg tiles.
// cand0 = tile for (g>>1)==0, cand1 for (g>>1)==1. srcA/srcB supply e0-3/e4-7.
DEVI bf16x8 xfrag(uint2 c0, uint2 c1, int srcA, int srcB, bool hig) {
  uint2 a0 = shfl_u2(c0, srcA), a1 = shfl_u2(c1, srcA);
  uint2 b0 = shfl_u2(c0, srcB), b1 = shfl_u2(c1, srcB);
  uint2 lo = hig ? a1 : a0, hi = hig ? b1 : b0;
  union { unsigned u[4]; bf16x8 v; } r;
  r.u[0] = lo.x; r.u[1] = lo.y; r.u[2] = hi.x; r.u[3] = hi.y;
  return r.v;
}
DEVI uint2 pk4(const f32x4& a) {
  uint2 r; r.x = pkbf(a[0], a[1]); r.y = pkbf(a[2], a[3]); return r;
}

// ---------------- main fused kernel ----------------------------------------
__global__ __launch_bounds__(512, 2)
void attn_kernel(const float* __restrict__ x, const float* __restrict__ y,
                 const char* __restrict__ wsW, const float* __restrict__ biasD,
                 float* __restrict__ out) {
  extern __shared__ char smem[];
  char* xb = smem;                            // 50176
  char* yb = smem + 50176;                    // 50176
  const int tid = threadIdx.x;
  const int lane = tid & 63, wave = tid >> 6;
  const int g = lane >> 4, lr = lane & 15;
  char* kscr = smem + 100352 + wave * 3136;   // wave-private k transpose buf

  const int srcA = lr + ((g & 1) << 5);
  const int srcB = srcA + 16;
  const bool hig = g >= 2;

  const int bw = blockIdx.x;
  const float* xs = x + (size_t)bw * 25088;
  const float* ys = y + (size_t)bw * 25088;

  // ---- stage x,y -> LDS bf16 (only barrier in the kernel) ----
  for (int it = tid; it < 6272; it += 512) {
    float4 v = ((const float4*)xs)[it];
    float4 w = ((const float4*)ys)[it];
    int i = it >> 7;
    int k = (it & 127) << 2;
    unsigned a = ((unsigned)(i * 1024 + k * 2)) ^ SWZ_Y(i);
    uint2 ux, uy;
    ux.x = pkbf(v.x, v.y); ux.y = pkbf(v.z, v.w);
    uy.x = pkbf(w.x, w.y); uy.y = pkbf(w.z, w.w);
    *(uint2*)(xb + a) = ux;
    *(uint2*)(yb + a) = uy;
  }
  __syncthreads();

  const bf16x8* wsQ = (const bf16x8*)wsW;
  const bf16x8* wsK = (const bf16x8*)(wsW + 524288);
  const bf16x8* wsV = (const bf16x8*)(wsW + 1048576);
  const f32x4* bD = (const f32x4*)biasD;
  const f32x4 fz = {0.f, 0.f, 0.f, 0.f};

  for (int hh = 0; hh < 2; ++hh) {
    const int h = wave * 2 + hh;
    WAVE_DS_FENCE();  // prior head's k reads done before overwrite

    // ---------- Q^T pass: Q^T[dh 32][tok 64] = Wq^T @ X^T ----------
    f32x4 aQ[2][4];
    #pragma unroll
    for (int m = 0; m < 2; ++m)
      #pragma unroll
      for (int n = 0; n < 4; ++n) aQ[m][n] = fz;
    {
      const bf16x8* pQ0 = wsQ + (size_t)((h * 2 + 0) * 16) * 64 + lane;
      const bf16x8* pQ1 = wsQ + (size_t)((h * 2 + 1) * 16) * 64 + lane;
      bf16x8 ra[8], rb[8];
      #pragma unroll
      for (int i = 0; i < 8; ++i) { ra[i] = pQ0[i * 64]; rb[i] = pQ1[i * 64]; }
      #pragma unroll
      for (int ks = 0; ks < 16; ++ks) {
        bf16x8 w0 = ra[ks & 7], w1 = rb[ks & 7];
        if (ks < 8) { ra[ks & 7] = pQ0[(ks + 8) * 64]; rb[ks & 7] = pQ1[(ks + 8) * 64]; }
        int kc = ks * 32 + g * 8;
        bf16x8 b0 = ldXY(xb, lr, kc);
        bf16x8 b1 = ldXY(xb, lr + 16, kc);
        bf16x8 b2 = ldXY(xb, lr + 32, kc);
        bf16x8 b3 = ldXYc(xb, lr + 48, kc);
        aQ[0][0] = MFMA16(w0, b0, aQ[0][0]);
        aQ[0][1] = MFMA16(w0, b1, aQ[0][1]);
        aQ[0][2] = MFMA16(w0, b2, aQ[0][2]);
        aQ[0][3] = MFMA16(w0, b3, aQ[0][3]);
        aQ[1][0] = MFMA16(w1, b0, aQ[1][0]);
        aQ[1][1] = MFMA16(w1, b1, aQ[1][1]);
        aQ[1][2] = MFMA16(w1, b2, aQ[1][2]);
        aQ[1][3] = MFMA16(w1, b3, aQ[1][3]);
      }
    }
    uint2 pkQ[2][4];
    #pragma unroll
    for (int m = 0; m < 2; ++m)
      #pragma unroll
      for (int n = 0; n < 4; ++n) pkQ[m][n] = pk4(aQ[m][n]);

    // ---------- K,V pass (untransposed): [tok 64][dh 32] ----------
    f32x4 aK[4][2], aV[4][2];
    #pragma unroll
    for (int mt = 0; mt < 4; ++mt) {
      aK[mt][0] = fz; aK[mt][1] = fz; aV[mt][0] = fz; aV[mt][1] = fz;
    }
    {
      const bf16x8* pK0 = wsK + (size_t)((h * 2 + 0) * 16) * 64 + lane;
      const bf16x8* pK1 = wsK + (size_t)((h * 2 + 1) * 16) * 64 + lane;
      const bf16x8* pV0 = wsV + (size_t)((h * 2 + 0) * 16) * 64 + lane;
      const bf16x8* pV1 = wsV + (size_t)((h * 2 + 1) * 16) * 64 + lane;
      bf16x8 rk0[4], rk1[4], rv0[4], rv1[4];
      #pragma unroll
      for (int i = 0; i < 4; ++i) {
        rk0[i] = pK0[i * 64]; rk1[i] = pK1[i * 64];
        rv0[i] = pV0[i * 64]; rv1[i] = pV1[i * 64];
      }
      #pragma unroll
      for (int ks = 0; ks < 16; ++ks) {
        bf16x8 k0 = rk0[ks & 3], k1 = rk1[ks & 3];
        bf16x8 v0 = rv0[ks & 3], v1 = rv1[ks & 3];
        if (ks < 12) {
          rk0[ks & 3] = pK0[(ks + 4) * 64]; rk1[ks & 3] = pK1[(ks + 4) * 64];
          rv0[ks & 3] = pV0[(ks + 4) * 64]; rv1[ks & 3] = pV1[(ks + 4) * 64];
        }
        int kc = ks * 32 + g * 8;
        bf16x8 a0 = ldXY(yb, lr, kc);
        bf16x8 a1 = ldXY(yb, lr + 16, kc);
        bf16x8 a2 = ldXY(yb, lr + 32, kc);
        bf16x8 a3 = ldXYc(yb, lr + 48, kc);
        aK[0][0] = MFMA16(a0, k0, aK[0][0]);
        aK[1][0] = MFMA16(a1, k0, aK[1][0]);
        aK[2][0] = MFMA16(a2, k0, aK[2][0]);
        aK[3][0] = MFMA16(a3, k0, aK[3][0]);
        aK[0][1] = MFMA16(a0, k1, aK[0][1]);
        aK[1][1] = MFMA16(a1, k1, aK[1][1]);
        aK[2][1] = MFMA16(a2, k1, aK[2][1]);
        aK[3][1] = MFMA16(a3, k1, aK[3][1]);
        aV[0][0] = MFMA16(a0, v0, aV[0][0]);
        aV[1][0] = MFMA16(a1, v0, aV[1][0]);
        aV[2][0] = MFMA16(a2, v0, aV[2][0]);
        aV[3][0] = MFMA16(a3, v0, aV[3][0]);
        aV[0][1] = MFMA16(a0, v1, aV[0][1]);
        aV[1][1] = MFMA16(a1, v1, aV[1][1]);
        aV[2][1] = MFMA16(a2, v1, aV[2][1]);
        aV[3][1] = MFMA16(a3, v1, aV[3][1]);
      }
    }
    // k -> wave-private LDS transpose ([tok][dh], swizzled)
    #pragma unroll
    for (int mt = 0; mt < 4; ++mt)
      #pragma unroll
      for (int nt = 0; nt < 2; ++nt)
        #pragma unroll
        for (int r = 0; r < 4; ++r) {
          int row = mt * 16 + g * 4 + r;
          if (row < 49) {
            unsigned a = ((unsigned)(row * 64 + (nt * 16 + lr) * 2)) ^ SWZ_A(row);
            *(unsigned short*)(kscr + a) = f2bf(aK[mt][nt][r]);
          }
        }
    uint2 pkV[4][2];
    #pragma unroll
    for (int mt = 0; mt < 4; ++mt) {
      pkV[mt][0] = pk4(aV[mt][0]);
      pkV[mt][1] = pk4(aV[mt][1]);
    }
    WAVE_DS_FENCE();
    bf16x8 kf[4];
    #pragma unroll
    for (int jt = 0; jt < 4; ++jt) kf[jt] = ldA(kscr, jt * 16 + lr, g * 8);

    // ---------- sim^T + softmax, streamed per i-tile ----------
    uint2 pkP[4][4];
    f32x4 bnext[4];
    #pragma unroll
    for (int jt = 0; jt < 4; ++jt)
      bnext[jt] = bD[(size_t)(((h * 4 + 0) * 4 + jt) * 64 + lane)];
    #pragma unroll
    for (int it = 0; it < 4; ++it) {
      f32x4 bs[4];
      #pragma unroll
      for (int jt = 0; jt < 4; ++jt) bs[jt] = bnext[jt];
      if (it < 3) {
        #pragma unroll
        for (int jt = 0; jt < 4; ++jt)
          bnext[jt] = bD[(size_t)(((h * 4 + it + 1) * 4 + jt) * 64 + lane)];
      }
      bf16x8 qf = xfrag(pkQ[0][it], pkQ[1][it], srcA, srcB, hig);
      f32x4 vals[4];
      #pragma unroll
      for (int jt = 0; jt < 4; ++jt) vals[jt] = MFMA16(kf[jt], qf, fz);
      #pragma unroll
      for (int jt = 0; jt < 4; ++jt) vals[jt] = vals[jt] + bs[jt];
      float m = vals[0][0];
      #pragma unroll
      for (int jt = 0; jt < 4; ++jt)
        #pragma unroll
        for (int r = 0; r < 4; ++r) m = fmaxf(m, vals[jt][r]);
      m = fmaxf(m, __shfl_xor(m, 16));
      m = fmaxf(m, __shfl_xor(m, 32));
      float s = 0.f;
      #pragma unroll
      for (int jt = 0; jt < 4; ++jt)
        #pragma unroll
        for (int r = 0; r < 4; ++r) {
          float pv = __expf(vals[jt][r] - m);
          vals[jt][r] = pv;
          s += pv;
        }
      s += __shfl_xor(s, 16);
      s += __shfl_xor(s, 32);
      float inv = 1.0f / s;
      #pragma unroll
      for (int jt = 0; jt < 4; ++jt) {
        pkP[it][jt].x = pkbf(vals[jt][0] * inv, vals[jt][1] * inv);
        pkP[it][jt].y = pkbf(vals[jt][2] * inv, vals[jt][3] * inv);
      }
    }

    // ---------- PV: out^T[dh][i] = V^T @ P^T (all operands via shfl) --------
    f32x4 acco[2][4];
    #pragma unroll
    for (int md = 0; md < 2; ++md)
      #pragma unroll
      for (int it = 0; it < 4; ++it) acco[md][it] = fz;
    #pragma unroll
    for (int ks = 0; ks < 2; ++ks) {
      bf16x8 aV0 = xfrag(pkV[ks * 2][0], pkV[ks * 2 + 1][0], srcA, srcB, hig);
      bf16x8 aV1 = xfrag(pkV[ks * 2][1], pkV[ks * 2 + 1][1], srcA, srcB, hig);
      #pragma unroll
      for (int it = 0; it < 4; ++it) {
        bf16x8 bP = xfrag(pkP[it][ks * 2], pkP[it][ks * 2 + 1], srcA, srcB, hig);
        acco[0][it] = MFMA16(aV0, bP, acco[0][it]);
        acco[1][it] = MFMA16(aV1, bP, acco[1][it]);
      }
    }

    // ---------- store (already normalized) ----------
    float* ow = out + (size_t)bw * 25088 + h * 32;
    #pragma unroll
    for (int it = 0; it < 4; ++it) {
      int tok = it * 16 + lr;
      if (tok < 49) {
        #pragma unroll
        for (int md = 0; md < 2; ++md)
          *(f32x4*)(&ow[(size_t)tok * 512 + md * 16 + g * 4]) = acco[md][it];
      }
    }
  }
}

extern "C" void kernel_launch(void* const* d_in, const int* in_sizes, int n_in,
                              void* d_out, int out_size, void* d_ws, size_t ws_size,
                              hipStream_t stream) {
  (void)in_sizes; (void)n_in; (void)out_size; (void)ws_size;
  const float* x = (const float*)d_in[0];
  const float* y = (const float*)d_in[1];
  const float* Wq = (const float*)d_in[2];
  const float* Wkv = (const float*)d_in[3];
  const float* bt = (const float*)d_in[4];
  float* out = (float*)d_out;
  char* ws = (char*)d_ws;

  prep_kernel<<<3072, 256, 0, stream>>>(Wq, Wkv, bt, ws);

  (void)hipFuncSetAttribute((const void*)attn_kernel,
                            hipFuncAttributeMaxDynamicSharedMemorySize, 125440);
  attn_kernel<<<4096, 512, 125440, stream>>>(x, y, (const char*)ws,
                                             (const float*)(ws + 1572864), out);
}